// Round 6
// baseline (268.317 us; speedup 1.0000x reference)
//
#include <hip/hip_runtime.h>

// YOLOv1 loss: batch x 7 x 7 x 30 fp32 (y_trues, y_preds) -> scalar.
// History: R1 strided dwordx2 77us | R2 LDS-stage 96us | R3 strided dwordx4
// (2 cells/thr) 80us | R4 async global_load_lds coalesced 96us.
// Four shapes, one 77-96us band; duration does NOT track FETCH_SIZE (94 vs
// 190 MB at same time), nor coalescing, nor occupancy, nor VALU. Surviving
// theory: per-CU L1(TCP) outstanding-line-miss limit (MSHR): ~5.9k unique
// 128B lines/CU x ~500cyc miss latency / ~16 trackers ~= 77us. Every variant
// misses each line exactly once => identical time.
// R5 (fixed compile): R3 shape + __builtin_nontemporal_load (nt flag =
// no-allocate/streaming) on all global loads to bypass L1 line allocation.
// Builtin requires native clang vector type, not HIP_vector_type.

#define SS 49
#define DD 30

typedef float f32x4 __attribute__((ext_vector_type(4)));

__device__ __forceinline__ float cell_loss(const float* __restrict__ yt,
                                           const float* __restrict__ yp) {
    const float LAMBDA_COORD = 5.0f;
    const float LAMBDA_NOOBJ = 0.5f;
    const float EPS = 1e-6f;

    float obj = (yt[4] == 1.0f) ? 1.0f : 0.0f;
    float noobj = 1.0f - obj;

    float tx1 = yt[0] - yt[2] * 0.5f, ty1 = yt[1] - yt[3] * 0.5f;
    float tx2 = yt[0] + yt[2] * 0.5f, ty2 = yt[1] + yt[3] * 0.5f;
    float ta = fabsf((tx2 - tx1) * (ty2 - ty1));

    float ax1 = yp[0] - yp[2] * 0.5f, ay1 = yp[1] - yp[3] * 0.5f;
    float ax2 = yp[0] + yp[2] * 0.5f, ay2 = yp[1] + yp[3] * 0.5f;
    float iw1 = fmaxf(fminf(tx2, ax2) - fmaxf(tx1, ax1), 0.0f);
    float ih1 = fmaxf(fminf(ty2, ay2) - fmaxf(ty1, ay1), 0.0f);
    float inter1 = iw1 * ih1;
    float aa = fabsf((ax2 - ax1) * (ay2 - ay1));
    float iou1 = inter1 / (ta + aa - inter1 + EPS);

    float bx1 = yp[5] - yp[7] * 0.5f, by1 = yp[6] - yp[8] * 0.5f;
    float bx2 = yp[5] + yp[7] * 0.5f, by2 = yp[6] + yp[8] * 0.5f;
    float iw2 = fmaxf(fminf(tx2, bx2) - fmaxf(tx1, bx1), 0.0f);
    float ih2 = fmaxf(fminf(ty2, by2) - fmaxf(ty1, by1), 0.0f);
    float inter2 = iw2 * ih2;
    float ba = fabsf((bx2 - bx1) * (by2 - by1));
    float iou2 = inter2 / (ta + ba - inter2 + EPS);

    bool best1 = iou1 > iou2;
    float bh0 = best1 ? yp[0] : yp[5];
    float bh1 = best1 ? yp[1] : yp[6];
    float bh2 = best1 ? yp[2] : yp[7];
    float bh3 = best1 ? yp[3] : yp[8];
    float conf_hat       = best1 ? yp[4] : yp[9];
    float other_conf_hat = best1 ? yp[9] : yp[4];

    float dx = yt[0] - bh0, dy = yt[1] - bh1;
    float xy = dx * dx + dy * dy;

    float sw = sqrtf(yt[2]) - sqrtf(fabsf(bh2 + EPS));
    float sh = sqrtf(yt[3]) - sqrtf(fabsf(bh3 + EPS));
    float wh = sw * sw + sh * sh;

    float dc = yt[4] - conf_hat;
    float obj_conf = dc * dc;

    float noobj_in_obj = LAMBDA_NOOBJ * other_conf_hat * other_conf_hat;

    float d4 = yt[4] - yp[4];
    float d9 = yt[4] - yp[9];
    float noobj_cells = LAMBDA_NOOBJ * (d4 * d4 + d9 * d9);

    float cls = 0.0f;
#pragma unroll
    for (int k = 10; k < DD; ++k) {
        float d = yt[k] - yp[k];
        cls += d * d;
    }

    return obj * (LAMBDA_COORD * (xy + wh) + obj_conf + noobj_in_obj + cls)
         + noobj * noobj_cells;
}

__global__ __launch_bounds__(256)
void yolo_loss_kernel(const f32x4* __restrict__ yt4,
                      const f32x4* __restrict__ yp4,
                      float* __restrict__ out,
                      int npairs, float inv_batch) {
    int pair = blockIdx.x * blockDim.x + threadIdx.x;
    float acc = 0.0f;

    if (pair < npairs) {
        // 2 cells = 60 floats = 15 float4, 16B-aligned (240B chunk).
        const f32x4* tb = yt4 + (size_t)pair * 15;
        const f32x4* pb = yp4 + (size_t)pair * 15;
        float t[60], p[60];
#pragma unroll
        for (int i = 0; i < 15; ++i) {
            f32x4 v = __builtin_nontemporal_load(&tb[i]);
            t[4 * i + 0] = v.x; t[4 * i + 1] = v.y;
            t[4 * i + 2] = v.z; t[4 * i + 3] = v.w;
        }
#pragma unroll
        for (int i = 0; i < 15; ++i) {
            f32x4 v = __builtin_nontemporal_load(&pb[i]);
            p[4 * i + 0] = v.x; p[4 * i + 1] = v.y;
            p[4 * i + 2] = v.z; p[4 * i + 3] = v.w;
        }
        acc = cell_loss(t, p) + cell_loss(t + DD, p + DD);
    }

    // Wave reduce (64 lanes) -> cross-wave LDS -> one atomic per block.
#pragma unroll
    for (int off = 32; off > 0; off >>= 1)
        acc += __shfl_down(acc, off, 64);

    __shared__ float wsum[4];
    int lane = threadIdx.x & 63;
    int wave = threadIdx.x >> 6;
    if (lane == 0) wsum[wave] = acc;
    __syncthreads();
    if (threadIdx.x == 0) {
        float s = wsum[0] + wsum[1] + wsum[2] + wsum[3];
        atomicAdd(out, s * inv_batch);
    }
}

extern "C" void kernel_launch(void* const* d_in, const int* in_sizes, int n_in,
                              void* d_out, int out_size, void* d_ws, size_t ws_size,
                              hipStream_t stream) {
    const f32x4* yt4 = (const f32x4*)d_in[0];
    const f32x4* yp4 = (const f32x4*)d_in[1];
    float* out = (float*)d_out;

    int total = in_sizes[0];          // batch * 49 * 30 floats
    int ncells = total / DD;
    int batch = ncells / SS;
    int npairs = ncells / 2;          // 802816 cells -> 401408 pairs

    (void)hipMemsetAsync(out, 0, sizeof(float), stream);

    int block = 256;
    int grid = (npairs + block - 1) / block;   // 1568 blocks exactly
    yolo_loss_kernel<<<grid, block, 0, stream>>>(yt4, yp4, out, npairs,
                                                 1.0f / (float)batch);
}